// Round 2
// baseline (244.322 us; speedup 1.0000x reference)
//
#include <hip/hip_runtime.h>
#include <math.h>

#define NN 10000
#define NE 100000
#define BN_EPS 1e-5f

// NOTE (gfx950 ISA): global_atomic_pk_add_f32 does NOT exist (packed atomics
// are f16/bf16 only). f32 atomics are scalar. This version removes the 9.6M
// float atomics entirely via a dst-CSR gather, built once and reused by both
// edge layers.

// ---------------------------------------------------------------------------
// K0: prep. Pre-transpose weights, zero accumulators and the CSR histogram.
// ---------------------------------------------------------------------------
__global__ __launch_bounds__(256) void k_prep(
    const float* __restrict__ w0, const float* __restrict__ b0,
    const float* __restrict__ root0,
    const float* __restrict__ w1, const float* __restrict__ b1,
    const float* __restrict__ root1,
    const float* __restrict__ s_w, const float* __restrict__ t_w,
    float* __restrict__ wT0, float* __restrict__ wT1, float* __restrict__ wstT,
    float* __restrict__ st0, float* __restrict__ st1, float* __restrict__ out,
    int* __restrict__ cnt)
{
  int gid = blockIdx.x * 256 + threadIdx.x;
  int gsz = gridDim.x * 256;
  for (int idx = gid; idx < 16 * 320; idx += gsz) {
    int i = idx / 320, c = idx - i * 320;
    float v;
    if (c < 256)      v = w0[(i * 32 + (c & 31)) * 8 + (c >> 5)];
    else if (c < 288) v = b0[i * 32 + (c - 256)];
    else              v = root0[i * 32 + (c - 288)];
    wT0[idx] = v;
  }
  for (int idx = gid; idx < 32 * 640; idx += gsz) {
    int i = idx / 640, c = idx - i * 640;
    float v;
    if (c < 512)      v = w1[(i * 64 + (c & 63)) * 8 + (c >> 6)];
    else if (c < 576) v = b1[i * 64 + (c - 512)];
    else              v = root1[i * 64 + (c - 576)];
    wT1[idx] = v;
  }
  for (int idx = gid; idx < 64 * 256; idx += gsz) {
    int i = idx >> 8, o = idx & 255;
    wstT[idx] = (o < 128) ? s_w[o * 64 + i] : t_w[(o - 128) * 64 + i];
  }
  for (int idx = gid; idx < 64 * 128; idx += gsz) out[idx] = 0.f;
  for (int idx = gid; idx < NN; idx += gsz) cnt[idx] = 0;
  if (gid < 64)  st0[gid] = 0.f;
  if (gid < 128) st1[gid] = 0.f;
}

// ---------------------------------------------------------------------------
// CSR build (by dst), shared by both edge layers.
// ---------------------------------------------------------------------------
__global__ __launch_bounds__(256) void k_hist(
    const int* __restrict__ ei, int* __restrict__ cnt)
{
  int gid = blockIdx.x * 256 + threadIdx.x;
  for (int e = gid; e < NE; e += gridDim.x * 256)
    atomicAdd(&cnt[ei[NE + e]], 1);
}

// Single-block exclusive scan of cnt[NN] -> off[NN+1]; cursor = off copy.
__global__ __launch_bounds__(1024) void k_scan(
    const int* __restrict__ cnt, int* __restrict__ off, int* __restrict__ cursor)
{
  __shared__ int part[1024];
  int t = threadIdx.x;
  int base = t * 10;                       // 1024*10 >= NN
  int loc[10];
  int s = 0;
#pragma unroll
  for (int i = 0; i < 10; ++i) {
    int idx = base + i;
    int v = (idx < NN) ? cnt[idx] : 0;
    loc[i] = s; s += v;
  }
  part[t] = s;
  __syncthreads();
  // Hillis-Steele inclusive scan over 1024 partials
  for (int d = 1; d < 1024; d <<= 1) {
    int v = (t >= d) ? part[t - d] : 0;
    __syncthreads();
    part[t] += v;
    __syncthreads();
  }
  int excl = (t > 0) ? part[t - 1] : 0;
#pragma unroll
  for (int i = 0; i < 10; ++i) {
    int idx = base + i;
    if (idx < NN) { int o = excl + loc[i]; off[idx] = o; cursor[idx] = o; }
  }
  if (t == 1023) off[NN] = part[1023];
}

__global__ __launch_bounds__(256) void k_fill(
    const int* __restrict__ ei, int* __restrict__ cursor, int* __restrict__ elist)
{
  int gid = blockIdx.x * 256 + threadIdx.x;
  for (int e = gid; e < NE; e += gridDim.x * 256) {
    int dst = ei[NE + e];
    int pos = atomicAdd(&cursor[dst], 1);
    elist[pos] = e;
  }
}

// ---------------------------------------------------------------------------
// K1: layer-0 node kernel, register-column GEMV (unchanged).
// ---------------------------------------------------------------------------
__global__ __launch_bounds__(320) void k_node0(
    const float* __restrict__ x, const float* __restrict__ wT0,
    const float* __restrict__ bias0,
    float* __restrict__ G0, float* __restrict__ h0)
{
  int c = threadIdx.x;
  float wc[16];
#pragma unroll
  for (int i = 0; i < 16; ++i) wc[i] = wT0[i * 320 + c];
  float bi = (c >= 288) ? bias0[c - 288] : 0.f;

  int n0 = blockIdx.x * 20;
  for (int n = n0; n < n0 + 20; n += 2) {
    const float4* xa = (const float4*)(x + n * 16);
    float a0 = 0.f, a1 = 0.f;
#pragma unroll
    for (int q = 0; q < 4; ++q) {
      float4 v0 = xa[q], v1 = xa[q + 4];
      a0 = fmaf(v0.x, wc[4 * q + 0], a0); a1 = fmaf(v1.x, wc[4 * q + 0], a1);
      a0 = fmaf(v0.y, wc[4 * q + 1], a0); a1 = fmaf(v1.y, wc[4 * q + 1], a1);
      a0 = fmaf(v0.z, wc[4 * q + 2], a0); a1 = fmaf(v1.z, wc[4 * q + 2], a1);
      a0 = fmaf(v0.w, wc[4 * q + 3], a0); a1 = fmaf(v1.w, wc[4 * q + 3], a1);
    }
    if (c < 288) {
      G0[n * 288 + c]       = a0;
      G0[(n + 1) * 288 + c] = a1;
    } else {
      h0[n * 32 + (c - 288)]       = a0 + bi;
      h0[(n + 1) * 32 + (c - 288)] = a1 + bi;
    }
  }
}

// ---------------------------------------------------------------------------
// K2: layer-0 GATHER. One wave per dst node: 16 col-lanes (2 cols each,
// float2) x 4 edge-subsets. Butterfly combine, ONE float2 store per lane
// pair -> zero float atomics.
// Grid: 2500 x 256 (4 waves/block, 1 node/wave).
// ---------------------------------------------------------------------------
__global__ __launch_bounds__(256) void k_agg0(
    const int* __restrict__ ei, const float* __restrict__ ea,
    const int* __restrict__ off, const int* __restrict__ elist,
    const float* __restrict__ G0, float* __restrict__ h0)
{
  int tid = threadIdx.x;
  int node = blockIdx.x * 4 + (tid >> 6);
  int q = (tid >> 4) & 3;
  int o = (tid & 15) * 2;
  int j0 = off[node], j1 = off[node + 1];
  float a0 = 0.f, a1 = 0.f;
  for (int j = j0 + q; j < j1; j += 4) {
    int e = elist[j];
    int src = ei[e];
    const float* gr = G0 + src * 288;
    const float* er = ea + e * 8;
    float m0 = gr[256 + o], m1 = gr[257 + o];
#pragma unroll
    for (int k = 0; k < 8; ++k) {
      float2 g = *(const float2*)(gr + k * 32 + o);
      float ek = er[k];
      m0 = fmaf(ek, g.x, m0);
      m1 = fmaf(ek, g.y, m1);
    }
    a0 += m0; a1 += m1;
  }
  a0 += __shfl_xor(a0, 16); a1 += __shfl_xor(a1, 16);
  a0 += __shfl_xor(a0, 32); a1 += __shfl_xor(a1, 32);
  if (q == 0) {
    float2* p = (float2*)(h0 + node * 32 + o);
    float2 v = *p;
    *p = make_float2(v.x + a0, v.y + a1);
  }
}

// ---------------------------------------------------------------------------
// K3/K6: per-column sum & sumsq over N rows (BN stats), atomic partials.
// ---------------------------------------------------------------------------
template <int C>
__global__ __launch_bounds__(256) void k_stats(
    const float* __restrict__ h, float* __restrict__ st)
{
  const int RPB = 256 / C;
  int tid = threadIdx.x;
  int col = tid % C, rg = tid / C;
  float s1 = 0.f, s2 = 0.f;
  int step = gridDim.x * RPB;
  for (int n = blockIdx.x * RPB + rg; n < NN; n += step) {
    float v = h[n * C + col];
    s1 += v; s2 += v * v;
  }
  __shared__ float l1[256], l2[256];
  l1[tid] = s1; l2[tid] = s2;
  __syncthreads();
  if (tid < C) {
    for (int r = 1; r < RPB; ++r) { s1 += l1[r * C + tid]; s2 += l2[r * C + tid]; }
    unsafeAtomicAdd(&st[tid], s1);
    unsafeAtomicAdd(&st[C + tid], s2);
  }
}

// ---------------------------------------------------------------------------
// K4a: x1 = relu(bn0(h0)), IN-PLACE on h0.
// ---------------------------------------------------------------------------
__global__ __launch_bounds__(256) void k_x1(
    float* __restrict__ h0, const float* __restrict__ st0,
    const float* __restrict__ g0, const float* __restrict__ be0)
{
  __shared__ float sc[32], sh[32];
  int tid = threadIdx.x;
  if (tid < 32) {
    float mu  = st0[tid] * (1.0f / NN);
    float var = st0[32 + tid] * (1.0f / NN) - mu * mu;
    float s   = g0[tid] * rsqrtf(var + BN_EPS);
    sc[tid] = s;
    sh[tid] = be0[tid] - mu * s;
  }
  __syncthreads();
  const int NV = NN * 8;  // float4 count
  for (int i = blockIdx.x * 256 + tid; i < NV; i += gridDim.x * 256) {
    float4 v = ((const float4*)h0)[i];
    int c0 = (i * 4) & 31;
    v.x = fmaxf(fmaf(v.x, sc[c0],     sh[c0]),     0.f);
    v.y = fmaxf(fmaf(v.y, sc[c0 + 1], sh[c0 + 1]), 0.f);
    v.z = fmaxf(fmaf(v.z, sc[c0 + 2], sh[c0 + 2]), 0.f);
    v.w = fmaxf(fmaf(v.w, sc[c0 + 3], sh[c0 + 3]), 0.f);
    ((float4*)h0)[i] = v;
  }
}

// ---------------------------------------------------------------------------
// K4b: layer-1 node kernel, register-column GEMV (unchanged).
// ---------------------------------------------------------------------------
__global__ __launch_bounds__(320) void k_node1(
    const float* __restrict__ x1, const float* __restrict__ wT1,
    const float* __restrict__ bias1,
    float* __restrict__ G1, float* __restrict__ h1)
{
  int t = threadIdx.x;
  float wa[32], wb[32];
#pragma unroll
  for (int i = 0; i < 32; ++i) {
    float2 w2 = *(const float2*)(wT1 + i * 640 + 2 * t);
    wa[i] = w2.x; wb[i] = w2.y;
  }
  float bia = 0.f, bib = 0.f;
  if (t >= 288) { bia = bias1[2 * (t - 288)]; bib = bias1[2 * (t - 288) + 1]; }

  int n0 = blockIdx.x * 20;
  for (int n = n0; n < n0 + 20; n += 2) {
    const float4* xa = (const float4*)(x1 + n * 32);
    float a00 = 0.f, a01 = 0.f, a10 = 0.f, a11 = 0.f;
#pragma unroll
    for (int q = 0; q < 8; ++q) {
      float4 v0 = xa[q], v1 = xa[q + 8];
      a00 = fmaf(v0.x, wa[4 * q + 0], a00); a01 = fmaf(v0.x, wb[4 * q + 0], a01);
      a00 = fmaf(v0.y, wa[4 * q + 1], a00); a01 = fmaf(v0.y, wb[4 * q + 1], a01);
      a00 = fmaf(v0.z, wa[4 * q + 2], a00); a01 = fmaf(v0.z, wb[4 * q + 2], a01);
      a00 = fmaf(v0.w, wa[4 * q + 3], a00); a01 = fmaf(v0.w, wb[4 * q + 3], a01);
      a10 = fmaf(v1.x, wa[4 * q + 0], a10); a11 = fmaf(v1.x, wb[4 * q + 0], a11);
      a10 = fmaf(v1.y, wa[4 * q + 1], a10); a11 = fmaf(v1.y, wb[4 * q + 1], a11);
      a10 = fmaf(v1.z, wa[4 * q + 2], a10); a11 = fmaf(v1.z, wb[4 * q + 2], a11);
      a10 = fmaf(v1.w, wa[4 * q + 3], a10); a11 = fmaf(v1.w, wb[4 * q + 3], a11);
    }
    if (t < 288) {
      *(float2*)(G1 + n * 576 + 2 * t)       = make_float2(a00, a01);
      *(float2*)(G1 + (n + 1) * 576 + 2 * t) = make_float2(a10, a11);
    } else {
      int o = 2 * (t - 288);
      *(float2*)(h1 + n * 64 + o)       = make_float2(a00 + bia, a01 + bib);
      *(float2*)(h1 + (n + 1) * 64 + o) = make_float2(a10 + bia, a11 + bib);
    }
  }
}

// ---------------------------------------------------------------------------
// K5: layer-1 GATHER. One wave per dst node: 32 col-lanes (2 cols each,
// float2) x 2 edge-subsets. Butterfly combine, one float2 store.
// Grid: 2500 x 256 (4 waves/block, 1 node/wave).
// ---------------------------------------------------------------------------
__global__ __launch_bounds__(256) void k_agg1(
    const int* __restrict__ ei, const float* __restrict__ ea,
    const int* __restrict__ off, const int* __restrict__ elist,
    const float* __restrict__ G1, float* __restrict__ h1)
{
  int tid = threadIdx.x;
  int node = blockIdx.x * 4 + (tid >> 6);
  int half = (tid >> 5) & 1;
  int o = (tid & 31) * 2;
  int j0 = off[node], j1 = off[node + 1];
  float a0 = 0.f, a1 = 0.f;
  for (int j = j0 + half; j < j1; j += 2) {
    int e = elist[j];
    int src = ei[e];
    const float* gr = G1 + src * 576;
    const float* er = ea + e * 8;
    float m0 = gr[512 + o], m1 = gr[513 + o];
#pragma unroll
    for (int k = 0; k < 8; ++k) {
      float2 g = *(const float2*)(gr + k * 64 + o);
      float ek = er[k];
      m0 = fmaf(ek, g.x, m0);
      m1 = fmaf(ek, g.y, m1);
    }
    a0 += m0; a1 += m1;
  }
  a0 += __shfl_xor(a0, 32); a1 += __shfl_xor(a1, 32);
  if (half == 0) {
    float2* p = (float2*)(h1 + node * 64 + o);
    float2 v = *p;
    *p = make_float2(v.x + a0, v.y + a1);
  }
}

// ---------------------------------------------------------------------------
// K6b: x2 = relu(bn1(h1)), IN-PLACE on h1.
// ---------------------------------------------------------------------------
__global__ __launch_bounds__(256) void k_x2(
    float* __restrict__ h1, const float* __restrict__ st1,
    const float* __restrict__ g1, const float* __restrict__ be1)
{
  __shared__ float sc[64], sh[64];
  int tid = threadIdx.x;
  if (tid < 64) {
    float mu  = st1[tid] * (1.0f / NN);
    float var = st1[64 + tid] * (1.0f / NN) - mu * mu;
    float s   = g1[tid] * rsqrtf(var + BN_EPS);
    sc[tid] = s;
    sh[tid] = be1[tid] - mu * s;
  }
  __syncthreads();
  const int NV = NN * 16;  // float4 count
  for (int i = blockIdx.x * 256 + tid; i < NV; i += gridDim.x * 256) {
    float4 v = ((const float4*)h1)[i];
    int c0 = (i * 4) & 63;
    v.x = fmaxf(fmaf(v.x, sc[c0],     sh[c0]),     0.f);
    v.y = fmaxf(fmaf(v.y, sc[c0 + 1], sh[c0 + 1]), 0.f);
    v.z = fmaxf(fmaf(v.z, sc[c0 + 2], sh[c0 + 2]), 0.f);
    v.w = fmaxf(fmaf(v.w, sc[c0 + 3], sh[c0 + 3]), 0.f);
    ((float4*)h1)[i] = v;
  }
}

// ---------------------------------------------------------------------------
// K7: head (unchanged).
// ---------------------------------------------------------------------------
__global__ __launch_bounds__(256) void k_head(
    const float* __restrict__ x2, const float* __restrict__ wstT,
    const float* __restrict__ s_b, const float* __restrict__ t_b,
    const int* __restrict__ batch, float* __restrict__ out)
{
  int tid = threadIdx.x;
  int c = tid & 127, g = tid >> 7;
  int n0 = blockIdx.x * 40 + g * 20;
  int n1 = n0 + 20;
  if (n0 >= NN) return;
  if (n1 > NN) n1 = NN;

  float wsr[64], wtr[64];
#pragma unroll
  for (int k = 0; k < 64; ++k) {
    wsr[k] = wstT[k * 256 + c];
    wtr[k] = wstT[k * 256 + 128 + c];
  }
  float sb = s_b[c], tb = t_b[c];

  int bcur = batch[n0];
  float facc = 0.f;
  for (int n = n0; n < n1; ++n) {
    const float4* xr = (const float4*)(x2 + (size_t)n * 64);
    float as = 0.f, at = 0.f;
#pragma unroll
    for (int q = 0; q < 16; ++q) {
      float4 xv = xr[q];
      as = fmaf(xv.x, wsr[4 * q + 0], as); at = fmaf(xv.x, wtr[4 * q + 0], at);
      as = fmaf(xv.y, wsr[4 * q + 1], as); at = fmaf(xv.y, wtr[4 * q + 1], at);
      as = fmaf(xv.z, wsr[4 * q + 2], as); at = fmaf(xv.z, wtr[4 * q + 2], at);
      as = fmaf(xv.w, wsr[4 * q + 3], as); at = fmaf(xv.w, wtr[4 * q + 3], at);
    }
    float sv = fminf(30.f, fmaxf(-30.f, as + sb));
    float tv = at + tb;
    float f  = tanhf(tv) / (1.f + expf(sv));
    int b = batch[n];
    if (b != bcur) {
      unsafeAtomicAdd(&out[bcur * 128 + c], facc);
      bcur = b; facc = 0.f;
    }
    facc += f;
  }
  unsafeAtomicAdd(&out[bcur * 128 + c], facc);
}

// ---------------------------------------------------------------------------
extern "C" void kernel_launch(void* const* d_in, const int* in_sizes, int n_in,
                              void* d_out, int out_size, void* d_ws, size_t ws_size,
                              hipStream_t stream)
{
  const float* x     = (const float*)d_in[0];
  const int*   ei    = (const int*)d_in[1];
  const float* ea    = (const float*)d_in[2];
  const int*   batch = (const int*)d_in[3];
  // d_in[4] edge_batch: unused by the reference
  const float* w0    = (const float*)d_in[5];
  const float* b0    = (const float*)d_in[6];
  const float* root0 = (const float*)d_in[7];
  const float* bias0 = (const float*)d_in[8];
  const float* g0    = (const float*)d_in[9];
  const float* be0   = (const float*)d_in[10];
  const float* w1    = (const float*)d_in[11];
  const float* b1    = (const float*)d_in[12];
  const float* root1 = (const float*)d_in[13];
  const float* bias1 = (const float*)d_in[14];
  const float* g1    = (const float*)d_in[15];
  const float* be1   = (const float*)d_in[16];
  const float* s_w   = (const float*)d_in[17];
  const float* s_b   = (const float*)d_in[18];
  const float* t_w   = (const float*)d_in[19];
  const float* t_b   = (const float*)d_in[20];
  float* out = (float*)d_out;

  float* ws   = (float*)d_ws;
  float* G0   = ws;  ws += 2880000;   // N*288
  float* G1   = ws;  ws += 5760000;   // N*576
  float* h0   = ws;  ws += 320000;    // N*32   (becomes x1 in-place)
  float* h1   = ws;  ws += 640000;    // N*64   (becomes x2 in-place)
  float* st0  = ws;  ws += 64;
  float* st1  = ws;  ws += 128;
  float* wstT = ws;  ws += 16384;     // 64x256 transposed head weights
  float* wT0  = ws;  ws += 5120;      // 16x320
  float* wT1  = ws;  ws += 20480;     // 32x640
  // CSR (ints) after the float region
  int* cnt    = (int*)ws;             // NN   (histogram, then reused as nothing)
  int* off    = cnt + NN;             // NN+1
  int* cursor = off + NN + 1;         // NN
  int* elist  = cursor + NN;          // NE

  hipLaunchKernelGGL(k_prep, dim3(64), dim3(256), 0, stream,
                     w0, b0, root0, w1, b1, root1, s_w, t_w,
                     wT0, wT1, wstT, st0, st1, out, cnt);
  hipLaunchKernelGGL(k_hist, dim3(256), dim3(256), 0, stream, ei, cnt);
  hipLaunchKernelGGL(k_scan, dim3(1), dim3(1024), 0, stream, cnt, off, cursor);
  hipLaunchKernelGGL(k_fill, dim3(256), dim3(256), 0, stream, ei, cursor, elist);
  hipLaunchKernelGGL(k_node0, dim3(500), dim3(320), 0, stream,
                     x, wT0, bias0, G0, h0);
  hipLaunchKernelGGL(k_agg0, dim3(2500), dim3(256), 0, stream,
                     ei, ea, off, elist, G0, h0);
  hipLaunchKernelGGL(k_stats<32>, dim3(64), dim3(256), 0, stream, h0, st0);
  hipLaunchKernelGGL(k_x1, dim3(160), dim3(256), 0, stream, h0, st0, g0, be0);
  hipLaunchKernelGGL(k_node1, dim3(500), dim3(320), 0, stream,
                     h0, wT1, bias1, G1, h1);
  hipLaunchKernelGGL(k_agg1, dim3(2500), dim3(256), 0, stream,
                     ei, ea, off, elist, G1, h1);
  hipLaunchKernelGGL(k_stats<64>, dim3(128), dim3(256), 0, stream, h1, st1);
  hipLaunchKernelGGL(k_x2, dim3(320), dim3(256), 0, stream, h1, st1, g1, be1);
  hipLaunchKernelGGL(k_head, dim3(250), dim3(256), 0, stream,
                     h1, wstT, s_b, t_b, batch, out);
}

// Round 3
// 244.266 us; speedup vs baseline: 1.0002x; 1.0002x over previous
//
#include <hip/hip_runtime.h>
#include <math.h>

#define NN 10000
#define NE 100000
#define BN_EPS 1e-5f

// Lessons so far (measured):
//  R1: global_atomic_pk_add_f32 does not exist on gfx950 (pk atomics are f16/bf16).
//  R2: dst-gather (zero float atomics, same 345MB G reads) REGRESSED 212->244us
//      => edge phase is read-bound, not atomic-bound.
//  R3: src-major scatter: read each G row once (regs), ea pre-gathered to
//      src order, keep scalar atomics. Edge reads 345MB -> ~30MB.

// ---------------------------------------------------------------------------
// K0: prep. Pre-transpose weights, zero out/stats/CSR histogram.
// ---------------------------------------------------------------------------
__global__ __launch_bounds__(256) void k_prep(
    const float* __restrict__ w0, const float* __restrict__ b0,
    const float* __restrict__ root0,
    const float* __restrict__ w1, const float* __restrict__ b1,
    const float* __restrict__ root1,
    const float* __restrict__ s_w, const float* __restrict__ t_w,
    float* __restrict__ wT0, float* __restrict__ wT1, float* __restrict__ wstT,
    float* __restrict__ st0, float* __restrict__ st1, float* __restrict__ out,
    int* __restrict__ cnt)
{
  int gid = blockIdx.x * 256 + threadIdx.x;
  int gsz = gridDim.x * 256;
  for (int idx = gid; idx < 16 * 320; idx += gsz) {
    int i = idx / 320, c = idx - i * 320;
    float v;
    if (c < 256)      v = w0[(i * 32 + (c & 31)) * 8 + (c >> 5)];
    else if (c < 288) v = b0[i * 32 + (c - 256)];
    else              v = root0[i * 32 + (c - 288)];
    wT0[idx] = v;
  }
  for (int idx = gid; idx < 32 * 640; idx += gsz) {
    int i = idx / 640, c = idx - i * 640;
    float v;
    if (c < 512)      v = w1[(i * 64 + (c & 63)) * 8 + (c >> 6)];
    else if (c < 576) v = b1[i * 64 + (c - 512)];
    else              v = root1[i * 64 + (c - 576)];
    wT1[idx] = v;
  }
  for (int idx = gid; idx < 64 * 256; idx += gsz) {
    int i = idx >> 8, o = idx & 255;
    wstT[idx] = (o < 128) ? s_w[o * 64 + i] : t_w[(o - 128) * 64 + i];
  }
  for (int idx = gid; idx < 64 * 128; idx += gsz) out[idx] = 0.f;
  for (int idx = gid; idx < NN; idx += gsz) cnt[idx] = 0;
  if (gid < 64)  st0[gid] = 0.f;
  if (gid < 128) st1[gid] = 0.f;
}

// ---------------------------------------------------------------------------
// CSR build by SRC (shared by both edge layers).
// ---------------------------------------------------------------------------
__global__ __launch_bounds__(256) void k_hist(
    const int* __restrict__ ei, int* __restrict__ cnt)
{
  int gid = blockIdx.x * 256 + threadIdx.x;
  for (int e = gid; e < NE; e += gridDim.x * 256)
    atomicAdd(&cnt[ei[e]], 1);
}

// Single-block exclusive scan of cnt[NN] -> off[NN+1]; cursor = off copy.
__global__ __launch_bounds__(1024) void k_scan(
    const int* __restrict__ cnt, int* __restrict__ off, int* __restrict__ cursor)
{
  __shared__ int part[1024];
  int t = threadIdx.x;
  int base = t * 10;                       // 1024*10 >= NN
  int loc[10];
  int s = 0;
#pragma unroll
  for (int i = 0; i < 10; ++i) {
    int idx = base + i;
    int v = (idx < NN) ? cnt[idx] : 0;
    loc[i] = s; s += v;
  }
  part[t] = s;
  __syncthreads();
  for (int d = 1; d < 1024; d <<= 1) {
    int v = (t >= d) ? part[t - d] : 0;
    __syncthreads();
    part[t] += v;
    __syncthreads();
  }
  int excl = (t > 0) ? part[t - 1] : 0;
#pragma unroll
  for (int i = 0; i < 10; ++i) {
    int idx = base + i;
    if (idx < NN) { int o = excl + loc[i]; off[idx] = o; cursor[idx] = o; }
  }
  if (t == 1023) off[NN] = part[1023];
}

// Fill: src-sorted edge order; pre-gather ea rows and dst ids so the scatter
// kernels read them sequentially (R2 lesson: scattered ea reads hurt).
__global__ __launch_bounds__(256) void k_fill(
    const int* __restrict__ ei, const float* __restrict__ ea,
    int* __restrict__ cursor,
    float* __restrict__ ea_s, int* __restrict__ dst_s)
{
  int gid = blockIdx.x * 256 + threadIdx.x;
  for (int e = gid; e < NE; e += gridDim.x * 256) {
    int src = ei[e];
    int pos = atomicAdd(&cursor[src], 1);
    dst_s[pos] = ei[NE + e];
    const float4* s = (const float4*)(ea + (size_t)e * 8);
    float4 a = s[0], b = s[1];
    float4* d = (float4*)(ea_s + (size_t)pos * 8);
    d[0] = a; d[1] = b;
  }
}

// ---------------------------------------------------------------------------
// K1: layer-0 node kernel, register-column GEMV (unchanged from R0).
// ---------------------------------------------------------------------------
__global__ __launch_bounds__(320) void k_node0(
    const float* __restrict__ x, const float* __restrict__ wT0,
    const float* __restrict__ bias0,
    float* __restrict__ G0, float* __restrict__ h0)
{
  int c = threadIdx.x;
  float wc[16];
#pragma unroll
  for (int i = 0; i < 16; ++i) wc[i] = wT0[i * 320 + c];
  float bi = (c >= 288) ? bias0[c - 288] : 0.f;

  int n0 = blockIdx.x * 20;
  for (int n = n0; n < n0 + 20; n += 2) {
    const float4* xa = (const float4*)(x + n * 16);
    float a0 = 0.f, a1 = 0.f;
#pragma unroll
    for (int q = 0; q < 4; ++q) {
      float4 v0 = xa[q], v1 = xa[q + 4];
      a0 = fmaf(v0.x, wc[4 * q + 0], a0); a1 = fmaf(v1.x, wc[4 * q + 0], a1);
      a0 = fmaf(v0.y, wc[4 * q + 1], a0); a1 = fmaf(v1.y, wc[4 * q + 1], a1);
      a0 = fmaf(v0.z, wc[4 * q + 2], a0); a1 = fmaf(v1.z, wc[4 * q + 2], a1);
      a0 = fmaf(v0.w, wc[4 * q + 3], a0); a1 = fmaf(v1.w, wc[4 * q + 3], a1);
    }
    if (c < 288) {
      G0[n * 288 + c]       = a0;
      G0[(n + 1) * 288 + c] = a1;
    } else {
      h0[n * 32 + (c - 288)]       = a0 + bi;
      h0[(n + 1) * 32 + (c - 288)] = a1 + bi;
    }
  }
}

// ---------------------------------------------------------------------------
// K2: layer-0 SRC-MAJOR scatter. One wave per src node: G0 row in 5 regs/lane
// (halves split k 0..3 / 4..7), read ONCE. Per edge: one broadcast float4 of
// ea_s, 4 fma, xor-combine halves, half-wave scalar atomics to h0.
// Grid: 2500 x 256 (4 waves/block, 1 src/wave).
// ---------------------------------------------------------------------------
__global__ __launch_bounds__(256) void k_sedge0(
    const float* __restrict__ ea_s, const int* __restrict__ dst_s,
    const int* __restrict__ off, const float* __restrict__ G0,
    float* __restrict__ h0)
{
  int tid = threadIdx.x;
  int node = blockIdx.x * 4 + (tid >> 6);
  int o = tid & 31, h = (tid >> 5) & 1;
  const float* gr = G0 + node * 288;
  float wr0 = gr[(h * 4 + 0) * 32 + o];
  float wr1 = gr[(h * 4 + 1) * 32 + o];
  float wr2 = gr[(h * 4 + 2) * 32 + o];
  float wr3 = gr[(h * 4 + 3) * 32 + o];
  float wr4 = (h == 0) ? gr[256 + o] : 0.f;   // per-edge msg bias (W b_nn part)
  int j0 = off[node], j1 = off[node + 1];
  for (int j = j0; j < j1; ++j) {
    float4 eav = ((const float4*)(ea_s + (size_t)j * 8))[h];
    float m = wr4;
    m = fmaf(eav.x, wr0, m);
    m = fmaf(eav.y, wr1, m);
    m = fmaf(eav.z, wr2, m);
    m = fmaf(eav.w, wr3, m);
    m += __shfl_xor(m, 32);
    if (h == 0) unsafeAtomicAdd(&h0[dst_s[j] * 32 + o], m);
  }
}

// ---------------------------------------------------------------------------
// K3/K6: per-column sum & sumsq over N rows (BN stats), atomic partials.
// ---------------------------------------------------------------------------
template <int C>
__global__ __launch_bounds__(256) void k_stats(
    const float* __restrict__ h, float* __restrict__ st)
{
  const int RPB = 256 / C;
  int tid = threadIdx.x;
  int col = tid % C, rg = tid / C;
  float s1 = 0.f, s2 = 0.f;
  int step = gridDim.x * RPB;
  for (int n = blockIdx.x * RPB + rg; n < NN; n += step) {
    float v = h[n * C + col];
    s1 += v; s2 += v * v;
  }
  __shared__ float l1[256], l2[256];
  l1[tid] = s1; l2[tid] = s2;
  __syncthreads();
  if (tid < C) {
    for (int r = 1; r < RPB; ++r) { s1 += l1[r * C + tid]; s2 += l2[r * C + tid]; }
    unsafeAtomicAdd(&st[tid], s1);
    unsafeAtomicAdd(&st[C + tid], s2);
  }
}

// ---------------------------------------------------------------------------
// K4a: x1 = relu(bn0(h0)), IN-PLACE on h0.
// ---------------------------------------------------------------------------
__global__ __launch_bounds__(256) void k_x1(
    float* __restrict__ h0, const float* __restrict__ st0,
    const float* __restrict__ g0, const float* __restrict__ be0)
{
  __shared__ float sc[32], sh[32];
  int tid = threadIdx.x;
  if (tid < 32) {
    float mu  = st0[tid] * (1.0f / NN);
    float var = st0[32 + tid] * (1.0f / NN) - mu * mu;
    float s   = g0[tid] * rsqrtf(var + BN_EPS);
    sc[tid] = s;
    sh[tid] = be0[tid] - mu * s;
  }
  __syncthreads();
  const int NV = NN * 8;  // float4 count
  for (int i = blockIdx.x * 256 + tid; i < NV; i += gridDim.x * 256) {
    float4 v = ((const float4*)h0)[i];
    int c0 = (i * 4) & 31;
    v.x = fmaxf(fmaf(v.x, sc[c0],     sh[c0]),     0.f);
    v.y = fmaxf(fmaf(v.y, sc[c0 + 1], sh[c0 + 1]), 0.f);
    v.z = fmaxf(fmaf(v.z, sc[c0 + 2], sh[c0 + 2]), 0.f);
    v.w = fmaxf(fmaf(v.w, sc[c0 + 3], sh[c0 + 3]), 0.f);
    ((float4*)h0)[i] = v;
  }
}

// ---------------------------------------------------------------------------
// K4b: layer-1 node kernel, register-column GEMV (unchanged from R0).
// ---------------------------------------------------------------------------
__global__ __launch_bounds__(320) void k_node1(
    const float* __restrict__ x1, const float* __restrict__ wT1,
    const float* __restrict__ bias1,
    float* __restrict__ G1, float* __restrict__ h1)
{
  int t = threadIdx.x;
  float wa[32], wb[32];
#pragma unroll
  for (int i = 0; i < 32; ++i) {
    float2 w2 = *(const float2*)(wT1 + i * 640 + 2 * t);
    wa[i] = w2.x; wb[i] = w2.y;
  }
  float bia = 0.f, bib = 0.f;
  if (t >= 288) { bia = bias1[2 * (t - 288)]; bib = bias1[2 * (t - 288) + 1]; }

  int n0 = blockIdx.x * 20;
  for (int n = n0; n < n0 + 20; n += 2) {
    const float4* xa = (const float4*)(x1 + n * 32);
    float a00 = 0.f, a01 = 0.f, a10 = 0.f, a11 = 0.f;
#pragma unroll
    for (int q = 0; q < 8; ++q) {
      float4 v0 = xa[q], v1 = xa[q + 8];
      a00 = fmaf(v0.x, wa[4 * q + 0], a00); a01 = fmaf(v0.x, wb[4 * q + 0], a01);
      a00 = fmaf(v0.y, wa[4 * q + 1], a00); a01 = fmaf(v0.y, wb[4 * q + 1], a01);
      a00 = fmaf(v0.z, wa[4 * q + 2], a00); a01 = fmaf(v0.z, wb[4 * q + 2], a01);
      a00 = fmaf(v0.w, wa[4 * q + 3], a00); a01 = fmaf(v0.w, wb[4 * q + 3], a01);
      a10 = fmaf(v1.x, wa[4 * q + 0], a10); a11 = fmaf(v1.x, wb[4 * q + 0], a11);
      a10 = fmaf(v1.y, wa[4 * q + 1], a10); a11 = fmaf(v1.y, wb[4 * q + 1], a11);
      a10 = fmaf(v1.z, wa[4 * q + 2], a10); a11 = fmaf(v1.z, wb[4 * q + 2], a11);
      a10 = fmaf(v1.w, wa[4 * q + 3], a10); a11 = fmaf(v1.w, wb[4 * q + 3], a11);
    }
    if (t < 288) {
      *(float2*)(G1 + n * 576 + 2 * t)       = make_float2(a00, a01);
      *(float2*)(G1 + (n + 1) * 576 + 2 * t) = make_float2(a10, a11);
    } else {
      int o = 2 * (t - 288);
      *(float2*)(h1 + n * 64 + o)       = make_float2(a00 + bia, a01 + bib);
      *(float2*)(h1 + (n + 1) * 64 + o) = make_float2(a10 + bia, a11 + bib);
    }
  }
}

// ---------------------------------------------------------------------------
// K5: layer-1 SRC-MAJOR scatter. One wave per src node: G1 row in 9 regs/lane
// (k 0..7 + W-bias), read ONCE (coalesced 256B). Per edge: two broadcast
// float4 of ea_s, 8 fma, one scalar atomic per lane to h1.
// Grid: 2500 x 256.
// ---------------------------------------------------------------------------
__global__ __launch_bounds__(256) void k_sedge1(
    const float* __restrict__ ea_s, const int* __restrict__ dst_s,
    const int* __restrict__ off, const float* __restrict__ G1,
    float* __restrict__ h1)
{
  int tid = threadIdx.x;
  int node = blockIdx.x * 4 + (tid >> 6);
  int o = tid & 63;
  const float* gr = G1 + node * 576;
  float w[8];
#pragma unroll
  for (int k = 0; k < 8; ++k) w[k] = gr[k * 64 + o];
  float wb = gr[512 + o];
  int j0 = off[node], j1 = off[node + 1];
  for (int j = j0; j < j1; ++j) {
    const float4* ep = (const float4*)(ea_s + (size_t)j * 8);
    float4 e0 = ep[0], e1 = ep[1];
    float m = wb;
    m = fmaf(e0.x, w[0], m); m = fmaf(e0.y, w[1], m);
    m = fmaf(e0.z, w[2], m); m = fmaf(e0.w, w[3], m);
    m = fmaf(e1.x, w[4], m); m = fmaf(e1.y, w[5], m);
    m = fmaf(e1.z, w[6], m); m = fmaf(e1.w, w[7], m);
    unsafeAtomicAdd(&h1[dst_s[j] * 64 + o], m);
  }
}

// ---------------------------------------------------------------------------
// K6b: x2 = relu(bn1(h1)), IN-PLACE on h1.
// ---------------------------------------------------------------------------
__global__ __launch_bounds__(256) void k_x2(
    float* __restrict__ h1, const float* __restrict__ st1,
    const float* __restrict__ g1, const float* __restrict__ be1)
{
  __shared__ float sc[64], sh[64];
  int tid = threadIdx.x;
  if (tid < 64) {
    float mu  = st1[tid] * (1.0f / NN);
    float var = st1[64 + tid] * (1.0f / NN) - mu * mu;
    float s   = g1[tid] * rsqrtf(var + BN_EPS);
    sc[tid] = s;
    sh[tid] = be1[tid] - mu * s;
  }
  __syncthreads();
  const int NV = NN * 16;  // float4 count
  for (int i = blockIdx.x * 256 + tid; i < NV; i += gridDim.x * 256) {
    float4 v = ((const float4*)h1)[i];
    int c0 = (i * 4) & 63;
    v.x = fmaxf(fmaf(v.x, sc[c0],     sh[c0]),     0.f);
    v.y = fmaxf(fmaf(v.y, sc[c0 + 1], sh[c0 + 1]), 0.f);
    v.z = fmaxf(fmaf(v.z, sc[c0 + 2], sh[c0 + 2]), 0.f);
    v.w = fmaxf(fmaf(v.w, sc[c0 + 3], sh[c0 + 3]), 0.f);
    ((float4*)h1)[i] = v;
  }
}

// ---------------------------------------------------------------------------
// K7: head (unchanged from R0).
// ---------------------------------------------------------------------------
__global__ __launch_bounds__(256) void k_head(
    const float* __restrict__ x2, const float* __restrict__ wstT,
    const float* __restrict__ s_b, const float* __restrict__ t_b,
    const int* __restrict__ batch, float* __restrict__ out)
{
  int tid = threadIdx.x;
  int c = tid & 127, g = tid >> 7;
  int n0 = blockIdx.x * 40 + g * 20;
  int n1 = n0 + 20;
  if (n0 >= NN) return;
  if (n1 > NN) n1 = NN;

  float wsr[64], wtr[64];
#pragma unroll
  for (int k = 0; k < 64; ++k) {
    wsr[k] = wstT[k * 256 + c];
    wtr[k] = wstT[k * 256 + 128 + c];
  }
  float sb = s_b[c], tb = t_b[c];

  int bcur = batch[n0];
  float facc = 0.f;
  for (int n = n0; n < n1; ++n) {
    const float4* xr = (const float4*)(x2 + (size_t)n * 64);
    float as = 0.f, at = 0.f;
#pragma unroll
    for (int q = 0; q < 16; ++q) {
      float4 xv = xr[q];
      as = fmaf(xv.x, wsr[4 * q + 0], as); at = fmaf(xv.x, wtr[4 * q + 0], at);
      as = fmaf(xv.y, wsr[4 * q + 1], as); at = fmaf(xv.y, wtr[4 * q + 1], at);
      as = fmaf(xv.z, wsr[4 * q + 2], as); at = fmaf(xv.z, wtr[4 * q + 2], at);
      as = fmaf(xv.w, wsr[4 * q + 3], as); at = fmaf(xv.w, wtr[4 * q + 3], at);
    }
    float sv = fminf(30.f, fmaxf(-30.f, as + sb));
    float tv = at + tb;
    float f  = tanhf(tv) / (1.f + expf(sv));
    int b = batch[n];
    if (b != bcur) {
      unsafeAtomicAdd(&out[bcur * 128 + c], facc);
      bcur = b; facc = 0.f;
    }
    facc += f;
  }
  unsafeAtomicAdd(&out[bcur * 128 + c], facc);
}

// ---------------------------------------------------------------------------
extern "C" void kernel_launch(void* const* d_in, const int* in_sizes, int n_in,
                              void* d_out, int out_size, void* d_ws, size_t ws_size,
                              hipStream_t stream)
{
  const float* x     = (const float*)d_in[0];
  const int*   ei    = (const int*)d_in[1];
  const float* ea    = (const float*)d_in[2];
  const int*   batch = (const int*)d_in[3];
  // d_in[4] edge_batch: unused by the reference
  const float* w0    = (const float*)d_in[5];
  const float* b0    = (const float*)d_in[6];
  const float* root0 = (const float*)d_in[7];
  const float* bias0 = (const float*)d_in[8];
  const float* g0    = (const float*)d_in[9];
  const float* be0   = (const float*)d_in[10];
  const float* w1    = (const float*)d_in[11];
  const float* b1    = (const float*)d_in[12];
  const float* root1 = (const float*)d_in[13];
  const float* bias1 = (const float*)d_in[14];
  const float* g1    = (const float*)d_in[15];
  const float* be1   = (const float*)d_in[16];
  const float* s_w   = (const float*)d_in[17];
  const float* s_b   = (const float*)d_in[18];
  const float* t_w   = (const float*)d_in[19];
  const float* t_b   = (const float*)d_in[20];
  float* out = (float*)d_out;

  float* ws   = (float*)d_ws;
  float* G0   = ws;  ws += 2880000;   // N*288
  float* G1   = ws;  ws += 5760000;   // N*576
  float* h0   = ws;  ws += 320000;    // N*32   (becomes x1 in-place)
  float* h1   = ws;  ws += 640000;    // N*64   (becomes x2 in-place)
  float* st0  = ws;  ws += 64;
  float* st1  = ws;  ws += 128;
  float* wstT = ws;  ws += 16384;     // 64x256 transposed head weights
  float* wT0  = ws;  ws += 5120;      // 16x320
  float* wT1  = ws;  ws += 20480;     // 32x640
  float* ea_s = ws;  ws += NE * 8;    // src-sorted edge_attr (16B aligned)
  int* dst_s  = (int*)ws;             // NE   src-sorted dst ids
  int* cnt    = dst_s + NE;           // NN   out-degree histogram
  int* off    = cnt + NN;             // NN+1 src-CSR offsets
  int* cursor = off + NN + 1;         // NN   fill cursors

  hipLaunchKernelGGL(k_prep, dim3(64), dim3(256), 0, stream,
                     w0, b0, root0, w1, b1, root1, s_w, t_w,
                     wT0, wT1, wstT, st0, st1, out, cnt);
  hipLaunchKernelGGL(k_hist, dim3(256), dim3(256), 0, stream, ei, cnt);
  hipLaunchKernelGGL(k_scan, dim3(1), dim3(1024), 0, stream, cnt, off, cursor);
  hipLaunchKernelGGL(k_fill, dim3(256), dim3(256), 0, stream,
                     ei, ea, cursor, ea_s, dst_s);
  hipLaunchKernelGGL(k_node0, dim3(500), dim3(320), 0, stream,
                     x, wT0, bias0, G0, h0);
  hipLaunchKernelGGL(k_sedge0, dim3(2500), dim3(256), 0, stream,
                     ea_s, dst_s, off, G0, h0);
  hipLaunchKernelGGL(k_stats<32>, dim3(64), dim3(256), 0, stream, h0, st0);
  hipLaunchKernelGGL(k_x1, dim3(160), dim3(256), 0, stream, h0, st0, g0, be0);
  hipLaunchKernelGGL(k_node1, dim3(500), dim3(320), 0, stream,
                     h0, wT1, bias1, G1, h1);
  hipLaunchKernelGGL(k_sedge1, dim3(2500), dim3(256), 0, stream,
                     ea_s, dst_s, off, G1, h1);
  hipLaunchKernelGGL(k_stats<64>, dim3(128), dim3(256), 0, stream, h1, st1);
  hipLaunchKernelGGL(k_x2, dim3(320), dim3(256), 0, stream, h1, st1, g1, be1);
  hipLaunchKernelGGL(k_head, dim3(250), dim3(256), 0, stream,
                     h1, wstT, s_b, t_b, batch, out);
}

// Round 6
// 242.962 us; speedup vs baseline: 1.0056x; 1.0054x over previous
//
#include <hip/hip_runtime.h>
#include <math.h>

#define NN 10000
#define NE 100000
#define BN_EPS 1e-5f

// Lessons (measured):
//  R1: global_atomic_pk_add_f32 doesn't exist on gfx950 (pk atomics f16/bf16 only).
//  R2: dst-gather (no float atomics, same G reads) 244us (+32 vs R0's 212).
//  R3: src-scatter (atomics kept, G reads 345MB->30MB) 244us (+32).
//      Opposite edge restructurings, same +32us = +3 kernel launches
//      => per-dispatch overhead ~10us dominates; edge work is not the limit.
//  R4: cooperative megakernel failed correctness (absmax 51, bug unlocated);
//      grid.sync cross-XCD visibility suspect. Retreat.
//  R5: fuse within standard launches: 10 -> 7 dispatches (drop prep, x1, x2),
//      all inner loops identical to the proven 212us baseline.
//  R6: resubmit of R5 (round 5 bench was an infra failure; no data).

// ---------------------------------------------------------------------------
// K1: layer-0 node kernel, register-column GEMV. Reads raw weights (no prep).
// Also zeroes out/st0/st1 (completes before their consumers launch).
// Thread c owns output column c. Grid: 500 x 320.
// ---------------------------------------------------------------------------
__global__ __launch_bounds__(320) void k_node0(
    const float* __restrict__ x,
    const float* __restrict__ w0, const float* __restrict__ b0,
    const float* __restrict__ root0, const float* __restrict__ bias0,
    float* __restrict__ G0, float* __restrict__ h0,
    float* __restrict__ out, float* __restrict__ st0, float* __restrict__ st1)
{
  int tid = threadIdx.x;
  int gid = blockIdx.x * 320 + tid;
  for (int i = gid; i < 64 * 128; i += 500 * 320) out[i] = 0.f;
  if (gid < 64)  st0[gid] = 0.f;
  if (gid < 128) st1[gid] = 0.f;

  int c = tid;
  float wc[16];
  float bi = 0.f;
  if (c < 256) {
#pragma unroll
    for (int i = 0; i < 16; ++i) wc[i] = w0[(i * 32 + (c & 31)) * 8 + (c >> 5)];
  } else if (c < 288) {
#pragma unroll
    for (int i = 0; i < 16; ++i) wc[i] = b0[i * 32 + (c - 256)];
  } else {
#pragma unroll
    for (int i = 0; i < 16; ++i) wc[i] = root0[i * 32 + (c - 288)];
    bi = bias0[c - 288];
  }

  int n0 = blockIdx.x * 20;
  for (int n = n0; n < n0 + 20; n += 2) {
    const float4* xa = (const float4*)(x + n * 16);
    float a0 = 0.f, a1 = 0.f;
#pragma unroll
    for (int q = 0; q < 4; ++q) {
      float4 v0 = xa[q], v1 = xa[q + 4];
      a0 = fmaf(v0.x, wc[4 * q + 0], a0); a1 = fmaf(v1.x, wc[4 * q + 0], a1);
      a0 = fmaf(v0.y, wc[4 * q + 1], a0); a1 = fmaf(v1.y, wc[4 * q + 1], a1);
      a0 = fmaf(v0.z, wc[4 * q + 2], a0); a1 = fmaf(v1.z, wc[4 * q + 2], a1);
      a0 = fmaf(v0.w, wc[4 * q + 3], a0); a1 = fmaf(v1.w, wc[4 * q + 3], a1);
    }
    if (c < 288) {
      G0[n * 288 + c]       = a0;
      G0[(n + 1) * 288 + c] = a1;
    } else {
      h0[n * 32 + (c - 288)]       = a0 + bi;
      h0[(n + 1) * 32 + (c - 288)] = a1 + bi;
    }
  }
}

// ---------------------------------------------------------------------------
// K2: layer-0 edge kernel (unchanged from 212us baseline). Half-wave/edge.
// ---------------------------------------------------------------------------
__global__ __launch_bounds__(256) void k_edge0(
    const int* __restrict__ ei, const float* __restrict__ ea,
    const float* __restrict__ G0, float* __restrict__ h0)
{
  int tid = threadIdx.x;
  int e = blockIdx.x * 8 + (tid >> 5);
  if (e >= NE) return;
  int o = tid & 31;
  int src = ei[e], dst = ei[NE + e];
  const float* gr = G0 + src * 288;
  const float* er = ea + e * 8;
  float m = gr[256 + o];
#pragma unroll
  for (int k = 0; k < 8; ++k) m = fmaf(er[k], gr[k * 32 + o], m);
  unsafeAtomicAdd(&h0[dst * 32 + o], m);
}

// ---------------------------------------------------------------------------
// K3/K5: per-column sum & sumsq (BN stats), atomic partials (unchanged).
// ---------------------------------------------------------------------------
template <int C>
__global__ __launch_bounds__(256) void k_stats(
    const float* __restrict__ h, float* __restrict__ st)
{
  const int RPB = 256 / C;
  int tid = threadIdx.x;
  int col = tid % C, rg = tid / C;
  float s1 = 0.f, s2 = 0.f;
  int step = gridDim.x * RPB;
  for (int n = blockIdx.x * RPB + rg; n < NN; n += step) {
    float v = h[n * C + col];
    s1 += v; s2 += v * v;
  }
  __shared__ float l1[256], l2[256];
  l1[tid] = s1; l2[tid] = s2;
  __syncthreads();
  if (tid < C) {
    for (int r = 1; r < RPB; ++r) { s1 += l1[r * C + tid]; s2 += l2[r * C + tid]; }
    unsafeAtomicAdd(&st[tid], s1);
    unsafeAtomicAdd(&st[C + tid], s2);
  }
}

// ---------------------------------------------------------------------------
// K4: layer-1 node kernel with BN0+ReLU fused on the input rows (h0 stays
// raw; x1 never materialized). Thread t owns cols {2t, 2t+1}; raw weights.
// Grid: 500 x 320.
// ---------------------------------------------------------------------------
__global__ __launch_bounds__(320) void k_node1(
    const float* __restrict__ h0raw,
    const float* __restrict__ st0, const float* __restrict__ g0,
    const float* __restrict__ be0,
    const float* __restrict__ w1, const float* __restrict__ b1,
    const float* __restrict__ root1, const float* __restrict__ bias1,
    float* __restrict__ G1, float* __restrict__ h1)
{
  __shared__ float sc[32], sh[32];
  int t = threadIdx.x;
  if (t < 32) {
    float mu  = st0[t] * (1.0f / NN);
    float var = st0[32 + t] * (1.0f / NN) - mu * mu;
    float s   = g0[t] * rsqrtf(var + BN_EPS);
    sc[t] = s;
    sh[t] = be0[t] - mu * s;
  }
  __syncthreads();

  float wa[32], wb[32];
  float bia = 0.f, bib = 0.f;
  {
    int cA = 2 * t;
    if (cA < 512) {
#pragma unroll
      for (int i = 0; i < 32; ++i) {
        int r = i * 64 + (cA & 63);
        wa[i] = w1[r * 8 + (cA >> 6)];
        wb[i] = w1[(r + 1) * 8 + (cA >> 6)];
      }
    } else if (cA < 576) {
#pragma unroll
      for (int i = 0; i < 32; ++i) {
        wa[i] = b1[i * 64 + (cA - 512)];
        wb[i] = b1[i * 64 + (cA - 511)];
      }
    } else {
#pragma unroll
      for (int i = 0; i < 32; ++i) {
        wa[i] = root1[i * 64 + (cA - 576)];
        wb[i] = root1[i * 64 + (cA - 575)];
      }
      bia = bias1[cA - 576];
      bib = bias1[cA - 575];
    }
  }

  int n0 = blockIdx.x * 20;
  for (int n = n0; n < n0 + 20; n += 2) {
    const float4* xa = (const float4*)(h0raw + n * 32);
    float a00 = 0.f, a01 = 0.f, a10 = 0.f, a11 = 0.f;
#pragma unroll
    for (int q = 0; q < 8; ++q) {
      float4 v0 = xa[q], v1 = xa[q + 8];   // rows n and n+1, cols 4q..4q+3
      int c0 = 4 * q;
      v0.x = fmaxf(fmaf(v0.x, sc[c0],     sh[c0]),     0.f);
      v0.y = fmaxf(fmaf(v0.y, sc[c0 + 1], sh[c0 + 1]), 0.f);
      v0.z = fmaxf(fmaf(v0.z, sc[c0 + 2], sh[c0 + 2]), 0.f);
      v0.w = fmaxf(fmaf(v0.w, sc[c0 + 3], sh[c0 + 3]), 0.f);
      v1.x = fmaxf(fmaf(v1.x, sc[c0],     sh[c0]),     0.f);
      v1.y = fmaxf(fmaf(v1.y, sc[c0 + 1], sh[c0 + 1]), 0.f);
      v1.z = fmaxf(fmaf(v1.z, sc[c0 + 2], sh[c0 + 2]), 0.f);
      v1.w = fmaxf(fmaf(v1.w, sc[c0 + 3], sh[c0 + 3]), 0.f);
      a00 = fmaf(v0.x, wa[4*q+0], a00); a01 = fmaf(v0.x, wb[4*q+0], a01);
      a00 = fmaf(v0.y, wa[4*q+1], a00); a01 = fmaf(v0.y, wb[4*q+1], a01);
      a00 = fmaf(v0.z, wa[4*q+2], a00); a01 = fmaf(v0.z, wb[4*q+2], a01);
      a00 = fmaf(v0.w, wa[4*q+3], a00); a01 = fmaf(v0.w, wb[4*q+3], a01);
      a10 = fmaf(v1.x, wa[4*q+0], a10); a11 = fmaf(v1.x, wb[4*q+0], a11);
      a10 = fmaf(v1.y, wa[4*q+1], a10); a11 = fmaf(v1.y, wb[4*q+1], a11);
      a10 = fmaf(v1.z, wa[4*q+2], a10); a11 = fmaf(v1.z, wb[4*q+2], a11);
      a10 = fmaf(v1.w, wa[4*q+3], a10); a11 = fmaf(v1.w, wb[4*q+3], a11);
    }
    if (t < 288) {
      *(float2*)(G1 + n * 576 + 2 * t)       = make_float2(a00, a01);
      *(float2*)(G1 + (n + 1) * 576 + 2 * t) = make_float2(a10, a11);
    } else {
      int o = 2 * t - 576;
      *(float2*)(h1 + n * 64 + o)       = make_float2(a00 + bia, a01 + bib);
      *(float2*)(h1 + (n + 1) * 64 + o) = make_float2(a10 + bia, a11 + bib);
    }
  }
}

// ---------------------------------------------------------------------------
// K6: layer-1 edge kernel (unchanged). One wave per edge.
// ---------------------------------------------------------------------------
__global__ __launch_bounds__(256) void k_edge1(
    const int* __restrict__ ei, const float* __restrict__ ea,
    const float* __restrict__ G1, float* __restrict__ h1)
{
  int tid = threadIdx.x;
  int e = blockIdx.x * 4 + (tid >> 6);
  if (e >= NE) return;
  int o = tid & 63;
  int src = ei[e], dst = ei[NE + e];
  const float* gr = G1 + src * 576;
  const float* er = ea + e * 8;
  float m = gr[512 + o];
#pragma unroll
  for (int k = 0; k < 8; ++k) m = fmaf(er[k], gr[k * 64 + o], m);
  unsafeAtomicAdd(&h1[dst * 64 + o], m);
}

// ---------------------------------------------------------------------------
// K7: head with BN1+ReLU fused on input rows (h1 stays raw; x2 never
// materialized). Raw s_w/t_w reads. Grid: 250 x 256.
// ---------------------------------------------------------------------------
__global__ __launch_bounds__(256) void k_head(
    const float* __restrict__ h1raw,
    const float* __restrict__ st1, const float* __restrict__ g1,
    const float* __restrict__ be1,
    const float* __restrict__ s_w, const float* __restrict__ s_b,
    const float* __restrict__ t_w, const float* __restrict__ t_b,
    const int* __restrict__ batch, float* __restrict__ out)
{
  __shared__ float sc[64], sh[64];
  int tid = threadIdx.x;
  if (tid < 64) {
    float mu  = st1[tid] * (1.0f / NN);
    float var = st1[64 + tid] * (1.0f / NN) - mu * mu;
    float s   = g1[tid] * rsqrtf(var + BN_EPS);
    sc[tid] = s;
    sh[tid] = be1[tid] - mu * s;
  }
  __syncthreads();

  int c = tid & 127, g = tid >> 7;
  int n0 = blockIdx.x * 40 + g * 20;
  int n1 = n0 + 20;
  if (n0 >= NN) return;
  if (n1 > NN) n1 = NN;

  float wsr[64], wtr[64];
  const float4* swp = (const float4*)(s_w + c * 64);
  const float4* twp = (const float4*)(t_w + c * 64);
#pragma unroll
  for (int q = 0; q < 16; ++q) {
    float4 a = swp[q], b = twp[q];
    wsr[4*q+0] = a.x; wsr[4*q+1] = a.y; wsr[4*q+2] = a.z; wsr[4*q+3] = a.w;
    wtr[4*q+0] = b.x; wtr[4*q+1] = b.y; wtr[4*q+2] = b.z; wtr[4*q+3] = b.w;
  }
  float sb = s_b[c], tb = t_b[c];

  int bcur = batch[n0];
  float facc = 0.f;
  for (int n = n0; n < n1; ++n) {
    const float4* xr = (const float4*)(h1raw + (size_t)n * 64);
    float as = 0.f, at = 0.f;
#pragma unroll
    for (int q = 0; q < 16; ++q) {
      float4 xv = xr[q];
      int c0 = 4 * q;
      xv.x = fmaxf(fmaf(xv.x, sc[c0],     sh[c0]),     0.f);
      xv.y = fmaxf(fmaf(xv.y, sc[c0 + 1], sh[c0 + 1]), 0.f);
      xv.z = fmaxf(fmaf(xv.z, sc[c0 + 2], sh[c0 + 2]), 0.f);
      xv.w = fmaxf(fmaf(xv.w, sc[c0 + 3], sh[c0 + 3]), 0.f);
      as = fmaf(xv.x, wsr[4 * q + 0], as); at = fmaf(xv.x, wtr[4 * q + 0], at);
      as = fmaf(xv.y, wsr[4 * q + 1], as); at = fmaf(xv.y, wtr[4 * q + 1], at);
      as = fmaf(xv.z, wsr[4 * q + 2], as); at = fmaf(xv.z, wtr[4 * q + 2], at);
      as = fmaf(xv.w, wsr[4 * q + 3], as); at = fmaf(xv.w, wtr[4 * q + 3], at);
    }
    float sv = fminf(30.f, fmaxf(-30.f, as + sb));
    float tv = at + tb;
    float f  = tanhf(tv) / (1.f + expf(sv));
    int b = batch[n];
    if (b != bcur) {
      unsafeAtomicAdd(&out[bcur * 128 + c], facc);
      bcur = b; facc = 0.f;
    }
    facc += f;
  }
  unsafeAtomicAdd(&out[bcur * 128 + c], facc);
}

// ---------------------------------------------------------------------------
extern "C" void kernel_launch(void* const* d_in, const int* in_sizes, int n_in,
                              void* d_out, int out_size, void* d_ws, size_t ws_size,
                              hipStream_t stream)
{
  const float* x     = (const float*)d_in[0];
  const int*   ei    = (const int*)d_in[1];
  const float* ea    = (const float*)d_in[2];
  const int*   batch = (const int*)d_in[3];
  // d_in[4] edge_batch: unused by the reference
  const float* w0    = (const float*)d_in[5];
  const float* b0    = (const float*)d_in[6];
  const float* root0 = (const float*)d_in[7];
  const float* bias0 = (const float*)d_in[8];
  const float* g0    = (const float*)d_in[9];
  const float* be0   = (const float*)d_in[10];
  const float* w1    = (const float*)d_in[11];
  const float* b1    = (const float*)d_in[12];
  const float* root1 = (const float*)d_in[13];
  const float* bias1 = (const float*)d_in[14];
  const float* g1    = (const float*)d_in[15];
  const float* be1   = (const float*)d_in[16];
  const float* s_w   = (const float*)d_in[17];
  const float* s_b   = (const float*)d_in[18];
  const float* t_w   = (const float*)d_in[19];
  const float* t_b   = (const float*)d_in[20];
  float* out = (float*)d_out;

  float* ws   = (float*)d_ws;
  float* G0   = ws;  ws += 2880000;   // N*288
  float* G1   = ws;  ws += 5760000;   // N*576
  float* h0   = ws;  ws += 320000;    // N*32  (stays RAW pre-BN)
  float* h1   = ws;  ws += 640000;    // N*64  (stays RAW pre-BN)
  float* st0  = ws;  ws += 64;
  float* st1  = ws;  ws += 128;

  hipLaunchKernelGGL(k_node0, dim3(500), dim3(320), 0, stream,
                     x, w0, b0, root0, bias0, G0, h0, out, st0, st1);
  hipLaunchKernelGGL(k_edge0, dim3((NE + 7) / 8), dim3(256), 0, stream,
                     ei, ea, G0, h0);
  hipLaunchKernelGGL(k_stats<32>, dim3(64), dim3(256), 0, stream, h0, st0);
  hipLaunchKernelGGL(k_node1, dim3(500), dim3(320), 0, stream,
                     h0, st0, g0, be0, w1, b1, root1, bias1, G1, h1);
  hipLaunchKernelGGL(k_edge1, dim3((NE + 3) / 4), dim3(256), 0, stream,
                     ei, ea, G1, h1);
  hipLaunchKernelGGL(k_stats<64>, dim3(128), dim3(256), 0, stream, h1, st1);
  hipLaunchKernelGGL(k_head, dim3(250), dim3(256), 0, stream,
                     h1, st1, g1, be1, s_w, s_b, t_w, t_b, batch, out);
}

// Round 7
// 202.934 us; speedup vs baseline: 1.2039x; 1.1972x over previous
//
#include <hip/hip_runtime.h>
#include <math.h>

#define NN 10000
#define NE 100000
#define BN_EPS 1e-5f

// Lessons (measured):
//  R1: global_atomic_pk_add_f32 doesn't exist on gfx950 (pk atomics f16/bf16 only).
//  R2: dst-gather (no float atomics, same G reads) 244us.
//  R3: src-scatter (atomics kept, G reads 345MB->30MB) 244us.
//  R6: 7-dispatch fusion (3 fewer launches) 243us.
//      R0 baseline (this structure, f32 G) = 212us. Three different structures
//      all at 243-244 with identical fillBuffer calibrator (~45.5us, 5.9TB/s)
//      => launch-count is NOT the lever; structural churn uninformative.
//  R7: minimal delta on R0: store G0/G1 as bf16 (RTN). Edge-phase reads
//      350MB -> 180MB, G writes 35MB -> 17MB. Only 4 kernels touched.

__device__ __forceinline__ unsigned short f2bf(float f) {
  unsigned int u = __float_as_uint(f);
  u += 0x7FFF + ((u >> 16) & 1);          // round-to-nearest-even
  return (unsigned short)(u >> 16);
}
__device__ __forceinline__ float bf2f(unsigned short h) {
  return __uint_as_float(((unsigned int)h) << 16);
}

// ---------------------------------------------------------------------------
// K0: prep. Pre-transpose weights into column-major-by-output layouts and
// zero the accumulators. (unchanged from 212us baseline)
// ---------------------------------------------------------------------------
__global__ __launch_bounds__(256) void k_prep(
    const float* __restrict__ w0, const float* __restrict__ b0,
    const float* __restrict__ root0,
    const float* __restrict__ w1, const float* __restrict__ b1,
    const float* __restrict__ root1,
    const float* __restrict__ s_w, const float* __restrict__ t_w,
    float* __restrict__ wT0, float* __restrict__ wT1, float* __restrict__ wstT,
    float* __restrict__ st0, float* __restrict__ st1, float* __restrict__ out)
{
  int gid = blockIdx.x * 256 + threadIdx.x;
  int gsz = gridDim.x * 256;
  for (int idx = gid; idx < 16 * 320; idx += gsz) {
    int i = idx / 320, c = idx - i * 320;
    float v;
    if (c < 256)      v = w0[(i * 32 + (c & 31)) * 8 + (c >> 5)];
    else if (c < 288) v = b0[i * 32 + (c - 256)];
    else              v = root0[i * 32 + (c - 288)];
    wT0[idx] = v;
  }
  for (int idx = gid; idx < 32 * 640; idx += gsz) {
    int i = idx / 640, c = idx - i * 640;
    float v;
    if (c < 512)      v = w1[(i * 64 + (c & 63)) * 8 + (c >> 6)];
    else if (c < 576) v = b1[i * 64 + (c - 512)];
    else              v = root1[i * 64 + (c - 576)];
    wT1[idx] = v;
  }
  for (int idx = gid; idx < 64 * 256; idx += gsz) {
    int i = idx >> 8, o = idx & 255;
    wstT[idx] = (o < 128) ? s_w[o * 64 + i] : t_w[(o - 128) * 64 + i];
  }
  for (int idx = gid; idx < 64 * 128; idx += gsz) out[idx] = 0.f;
  if (gid < 64)  st0[gid] = 0.f;
  if (gid < 128) st1[gid] = 0.f;
}

// ---------------------------------------------------------------------------
// K1: layer-0 node GEMV (R0 structure). DELTA: G0 stored as bf16.
// ---------------------------------------------------------------------------
__global__ __launch_bounds__(320) void k_node0(
    const float* __restrict__ x, const float* __restrict__ wT0,
    const float* __restrict__ bias0,
    unsigned short* __restrict__ G0h, float* __restrict__ h0)
{
  int c = threadIdx.x;
  float wc[16];
#pragma unroll
  for (int i = 0; i < 16; ++i) wc[i] = wT0[i * 320 + c];
  float bi = (c >= 288) ? bias0[c - 288] : 0.f;

  int n0 = blockIdx.x * 20;
  for (int n = n0; n < n0 + 20; n += 2) {
    const float4* xa = (const float4*)(x + n * 16);
    float a0 = 0.f, a1 = 0.f;
#pragma unroll
    for (int q = 0; q < 4; ++q) {
      float4 v0 = xa[q], v1 = xa[q + 4];
      a0 = fmaf(v0.x, wc[4 * q + 0], a0); a1 = fmaf(v1.x, wc[4 * q + 0], a1);
      a0 = fmaf(v0.y, wc[4 * q + 1], a0); a1 = fmaf(v1.y, wc[4 * q + 1], a1);
      a0 = fmaf(v0.z, wc[4 * q + 2], a0); a1 = fmaf(v1.z, wc[4 * q + 2], a1);
      a0 = fmaf(v0.w, wc[4 * q + 3], a0); a1 = fmaf(v1.w, wc[4 * q + 3], a1);
    }
    if (c < 288) {
      G0h[n * 288 + c]       = f2bf(a0);
      G0h[(n + 1) * 288 + c] = f2bf(a1);
    } else {
      h0[n * 32 + (c - 288)]       = a0 + bi;
      h0[(n + 1) * 32 + (c - 288)] = a1 + bi;
    }
  }
}

// ---------------------------------------------------------------------------
// K2: layer-0 edge kernel (R0 structure). DELTA: reads bf16 G0.
// Half-wave (32 lanes) per edge; each k-slice read = 32x2B = 64B coalesced.
// ---------------------------------------------------------------------------
__global__ __launch_bounds__(256) void k_edge0(
    const int* __restrict__ ei, const float* __restrict__ ea,
    const unsigned short* __restrict__ G0h, float* __restrict__ h0)
{
  int tid = threadIdx.x;
  int e = blockIdx.x * 8 + (tid >> 5);
  if (e >= NE) return;
  int o = tid & 31;
  int src = ei[e], dst = ei[NE + e];
  const unsigned short* gr = G0h + src * 288;
  const float* er = ea + e * 8;
  float m = bf2f(gr[256 + o]);
#pragma unroll
  for (int k = 0; k < 8; ++k) m = fmaf(er[k], bf2f(gr[k * 32 + o]), m);
  unsafeAtomicAdd(&h0[dst * 32 + o], m);
}

// ---------------------------------------------------------------------------
// K3/K6: per-column sum & sumsq over N rows (BN stats). (unchanged)
// ---------------------------------------------------------------------------
template <int C>
__global__ __launch_bounds__(256) void k_stats(
    const float* __restrict__ h, float* __restrict__ st)
{
  const int RPB = 256 / C;
  int tid = threadIdx.x;
  int col = tid % C, rg = tid / C;
  float s1 = 0.f, s2 = 0.f;
  int step = gridDim.x * RPB;
  for (int n = blockIdx.x * RPB + rg; n < NN; n += step) {
    float v = h[n * C + col];
    s1 += v; s2 += v * v;
  }
  __shared__ float l1[256], l2[256];
  l1[tid] = s1; l2[tid] = s2;
  __syncthreads();
  if (tid < C) {
    for (int r = 1; r < RPB; ++r) { s1 += l1[r * C + tid]; s2 += l2[r * C + tid]; }
    unsafeAtomicAdd(&st[tid], s1);
    unsafeAtomicAdd(&st[C + tid], s2);
  }
}

// ---------------------------------------------------------------------------
// K4a: x1 = relu(bn0(h0)), IN-PLACE on h0. (unchanged)
// ---------------------------------------------------------------------------
__global__ __launch_bounds__(256) void k_x1(
    float* __restrict__ h0, const float* __restrict__ st0,
    const float* __restrict__ g0, const float* __restrict__ be0)
{
  __shared__ float sc[32], sh[32];
  int tid = threadIdx.x;
  if (tid < 32) {
    float mu  = st0[tid] * (1.0f / NN);
    float var = st0[32 + tid] * (1.0f / NN) - mu * mu;
    float s   = g0[tid] * rsqrtf(var + BN_EPS);
    sc[tid] = s;
    sh[tid] = be0[tid] - mu * s;
  }
  __syncthreads();
  const int NV = NN * 8;  // float4 count
  for (int i = blockIdx.x * 256 + tid; i < NV; i += gridDim.x * 256) {
    float4 v = ((const float4*)h0)[i];
    int c0 = (i * 4) & 31;
    v.x = fmaxf(fmaf(v.x, sc[c0],     sh[c0]),     0.f);
    v.y = fmaxf(fmaf(v.y, sc[c0 + 1], sh[c0 + 1]), 0.f);
    v.z = fmaxf(fmaf(v.z, sc[c0 + 2], sh[c0 + 2]), 0.f);
    v.w = fmaxf(fmaf(v.w, sc[c0 + 3], sh[c0 + 3]), 0.f);
    ((float4*)h0)[i] = v;
  }
}

// ---------------------------------------------------------------------------
// K4b: layer-1 node GEMV (R0 structure). DELTA: G1 stored as bf16 (ushort2).
// ---------------------------------------------------------------------------
__global__ __launch_bounds__(320) void k_node1(
    const float* __restrict__ x1, const float* __restrict__ wT1,
    const float* __restrict__ bias1,
    unsigned short* __restrict__ G1h, float* __restrict__ h1)
{
  int t = threadIdx.x;
  float wa[32], wb[32];
#pragma unroll
  for (int i = 0; i < 32; ++i) {
    float2 w2 = *(const float2*)(wT1 + i * 640 + 2 * t);
    wa[i] = w2.x; wb[i] = w2.y;
  }
  float bia = 0.f, bib = 0.f;
  if (t >= 288) { bia = bias1[2 * (t - 288)]; bib = bias1[2 * (t - 288) + 1]; }

  int n0 = blockIdx.x * 20;
  for (int n = n0; n < n0 + 20; n += 2) {
    const float4* xa = (const float4*)(x1 + n * 32);
    float a00 = 0.f, a01 = 0.f, a10 = 0.f, a11 = 0.f;
#pragma unroll
    for (int q = 0; q < 8; ++q) {
      float4 v0 = xa[q], v1 = xa[q + 8];
      a00 = fmaf(v0.x, wa[4 * q + 0], a00); a01 = fmaf(v0.x, wb[4 * q + 0], a01);
      a00 = fmaf(v0.y, wa[4 * q + 1], a00); a01 = fmaf(v0.y, wb[4 * q + 1], a01);
      a00 = fmaf(v0.z, wa[4 * q + 2], a00); a01 = fmaf(v0.z, wb[4 * q + 2], a01);
      a00 = fmaf(v0.w, wa[4 * q + 3], a00); a01 = fmaf(v0.w, wb[4 * q + 3], a01);
      a10 = fmaf(v1.x, wa[4 * q + 0], a10); a11 = fmaf(v1.x, wb[4 * q + 0], a11);
      a10 = fmaf(v1.y, wa[4 * q + 1], a10); a11 = fmaf(v1.y, wb[4 * q + 1], a11);
      a10 = fmaf(v1.z, wa[4 * q + 2], a10); a11 = fmaf(v1.z, wb[4 * q + 2], a11);
      a10 = fmaf(v1.w, wa[4 * q + 3], a10); a11 = fmaf(v1.w, wb[4 * q + 3], a11);
    }
    if (t < 288) {
      *(ushort2*)(G1h + n * 576 + 2 * t)       = make_ushort2(f2bf(a00), f2bf(a01));
      *(ushort2*)(G1h + (n + 1) * 576 + 2 * t) = make_ushort2(f2bf(a10), f2bf(a11));
    } else {
      int o = 2 * (t - 288);
      *(float2*)(h1 + n * 64 + o)       = make_float2(a00 + bia, a01 + bib);
      *(float2*)(h1 + (n + 1) * 64 + o) = make_float2(a10 + bia, a11 + bib);
    }
  }
}

// ---------------------------------------------------------------------------
// K5: layer-1 edge kernel (R0 structure). DELTA: reads bf16 G1.
// One wave per edge; each k-slice read = 64x2B = 128B coalesced.
// ---------------------------------------------------------------------------
__global__ __launch_bounds__(256) void k_edge1(
    const int* __restrict__ ei, const float* __restrict__ ea,
    const unsigned short* __restrict__ G1h, float* __restrict__ h1)
{
  int tid = threadIdx.x;
  int e = blockIdx.x * 4 + (tid >> 6);
  if (e >= NE) return;
  int o = tid & 63;
  int src = ei[e], dst = ei[NE + e];
  const unsigned short* gr = G1h + src * 576;
  const float* er = ea + e * 8;
  float m = bf2f(gr[512 + o]);
#pragma unroll
  for (int k = 0; k < 8; ++k) m = fmaf(er[k], bf2f(gr[k * 64 + o]), m);
  unsafeAtomicAdd(&h1[dst * 64 + o], m);
}

// ---------------------------------------------------------------------------
// K6b: x2 = relu(bn1(h1)), IN-PLACE on h1. (unchanged)
// ---------------------------------------------------------------------------
__global__ __launch_bounds__(256) void k_x2(
    float* __restrict__ h1, const float* __restrict__ st1,
    const float* __restrict__ g1, const float* __restrict__ be1)
{
  __shared__ float sc[64], sh[64];
  int tid = threadIdx.x;
  if (tid < 64) {
    float mu  = st1[tid] * (1.0f / NN);
    float var = st1[64 + tid] * (1.0f / NN) - mu * mu;
    float s   = g1[tid] * rsqrtf(var + BN_EPS);
    sc[tid] = s;
    sh[tid] = be1[tid] - mu * s;
  }
  __syncthreads();
  const int NV = NN * 16;  // float4 count
  for (int i = blockIdx.x * 256 + tid; i < NV; i += gridDim.x * 256) {
    float4 v = ((const float4*)h1)[i];
    int c0 = (i * 4) & 63;
    v.x = fmaxf(fmaf(v.x, sc[c0],     sh[c0]),     0.f);
    v.y = fmaxf(fmaf(v.y, sc[c0 + 1], sh[c0 + 1]), 0.f);
    v.z = fmaxf(fmaf(v.z, sc[c0 + 2], sh[c0 + 2]), 0.f);
    v.w = fmaxf(fmaf(v.w, sc[c0 + 3], sh[c0 + 3]), 0.f);
    ((float4*)h1)[i] = v;
  }
}

// ---------------------------------------------------------------------------
// K7: head (unchanged from 212us baseline).
// ---------------------------------------------------------------------------
__global__ __launch_bounds__(256) void k_head(
    const float* __restrict__ x2, const float* __restrict__ wstT,
    const float* __restrict__ s_b, const float* __restrict__ t_b,
    const int* __restrict__ batch, float* __restrict__ out)
{
  int tid = threadIdx.x;
  int c = tid & 127, g = tid >> 7;
  int n0 = blockIdx.x * 40 + g * 20;
  int n1 = n0 + 20;
  if (n0 >= NN) return;
  if (n1 > NN) n1 = NN;

  float wsr[64], wtr[64];
#pragma unroll
  for (int k = 0; k < 64; ++k) {
    wsr[k] = wstT[k * 256 + c];
    wtr[k] = wstT[k * 256 + 128 + c];
  }
  float sb = s_b[c], tb = t_b[c];

  int bcur = batch[n0];
  float facc = 0.f;
  for (int n = n0; n < n1; ++n) {
    const float4* xr = (const float4*)(x2 + (size_t)n * 64);
    float as = 0.f, at = 0.f;
#pragma unroll
    for (int q = 0; q < 16; ++q) {
      float4 xv = xr[q];
      as = fmaf(xv.x, wsr[4 * q + 0], as); at = fmaf(xv.x, wtr[4 * q + 0], at);
      as = fmaf(xv.y, wsr[4 * q + 1], as); at = fmaf(xv.y, wtr[4 * q + 1], at);
      as = fmaf(xv.z, wsr[4 * q + 2], as); at = fmaf(xv.z, wtr[4 * q + 2], at);
      as = fmaf(xv.w, wsr[4 * q + 3], as); at = fmaf(xv.w, wtr[4 * q + 3], at);
    }
    float sv = fminf(30.f, fmaxf(-30.f, as + sb));
    float tv = at + tb;
    float f  = tanhf(tv) / (1.f + expf(sv));
    int b = batch[n];
    if (b != bcur) {
      unsafeAtomicAdd(&out[bcur * 128 + c], facc);
      bcur = b; facc = 0.f;
    }
    facc += f;
  }
  unsafeAtomicAdd(&out[bcur * 128 + c], facc);
}

// ---------------------------------------------------------------------------
extern "C" void kernel_launch(void* const* d_in, const int* in_sizes, int n_in,
                              void* d_out, int out_size, void* d_ws, size_t ws_size,
                              hipStream_t stream)
{
  const float* x     = (const float*)d_in[0];
  const int*   ei    = (const int*)d_in[1];
  const float* ea    = (const float*)d_in[2];
  const int*   batch = (const int*)d_in[3];
  // d_in[4] edge_batch: unused by the reference
  const float* w0    = (const float*)d_in[5];
  const float* b0    = (const float*)d_in[6];
  const float* root0 = (const float*)d_in[7];
  const float* bias0 = (const float*)d_in[8];
  const float* g0    = (const float*)d_in[9];
  const float* be0   = (const float*)d_in[10];
  const float* w1    = (const float*)d_in[11];
  const float* b1    = (const float*)d_in[12];
  const float* root1 = (const float*)d_in[13];
  const float* bias1 = (const float*)d_in[14];
  const float* g1    = (const float*)d_in[15];
  const float* be1   = (const float*)d_in[16];
  const float* s_w   = (const float*)d_in[17];
  const float* s_b   = (const float*)d_in[18];
  const float* t_w   = (const float*)d_in[19];
  const float* t_b   = (const float*)d_in[20];
  float* out = (float*)d_out;

  float* ws   = (float*)d_ws;
  unsigned short* G0h = (unsigned short*)ws;  ws += 1440000;  // N*288 bf16
  unsigned short* G1h = (unsigned short*)ws;  ws += 2880000;  // N*576 bf16
  float* h0   = ws;  ws += 320000;    // N*32   (becomes x1 in-place)
  float* h1   = ws;  ws += 640000;    // N*64   (becomes x2 in-place)
  float* st0  = ws;  ws += 64;
  float* st1  = ws;  ws += 128;
  float* wstT = ws;  ws += 16384;     // 64x256 transposed head weights
  float* wT0  = ws;  ws += 5120;      // 16x320
  float* wT1  = ws;  ws += 20480;     // 32x640

  hipLaunchKernelGGL(k_prep, dim3(64), dim3(256), 0, stream,
                     w0, b0, root0, w1, b1, root1, s_w, t_w,
                     wT0, wT1, wstT, st0, st1, out);
  hipLaunchKernelGGL(k_node0, dim3(500), dim3(320), 0, stream,
                     x, wT0, bias0, G0h, h0);
  hipLaunchKernelGGL(k_edge0, dim3((NE + 7) / 8), dim3(256), 0, stream,
                     ei, ea, G0h, h0);
  hipLaunchKernelGGL(k_stats<32>, dim3(64), dim3(256), 0, stream, h0, st0);
  hipLaunchKernelGGL(k_x1, dim3(160), dim3(256), 0, stream, h0, st0, g0, be0);
  hipLaunchKernelGGL(k_node1, dim3(500), dim3(320), 0, stream,
                     h0, wT1, bias1, G1h, h1);
  hipLaunchKernelGGL(k_edge1, dim3((NE + 3) / 4), dim3(256), 0, stream,
                     ei, ea, G1h, h1);
  hipLaunchKernelGGL(k_stats<64>, dim3(128), dim3(256), 0, stream, h1, st1);
  hipLaunchKernelGGL(k_x2, dim3(320), dim3(256), 0, stream, h1, st1, g1, be1);
  hipLaunchKernelGGL(k_head, dim3(250), dim3(256), 0, stream,
                     h1, wstT, s_b, t_b, batch, out);
}